// Round 17
// baseline (317.114 us; speedup 1.0000x reference)
//
#include <hip/hip_runtime.h>
#include <hip/hip_bf16.h>

#define B_ 16
#define I_ 256
#define O_ 256
#define T_ 512
#define L_ 8192
#define K_ 7
#define PAD_ 3
#define BN 32
#define NTILE 256
#define LDK 264   // Xs row stride in bf16 elements (256 + 8 pad)
#define XFS 39    // Xf row stride in floats (38-col window + round to odd: bank-spread)
#define XFN 2560  // 10*256 staged floats (covers 64*39=2496 + tail pad)

typedef unsigned short u16;
typedef unsigned int u32;
typedef __attribute__((ext_vector_type(8))) short short8;
typedef __attribute__((ext_vector_type(4))) float f32x4;

__device__ inline u16 f2bf(float f) {
    union { float f; u32 u; } v; v.f = f;
    u32 r = v.u + 0x7FFF + ((v.u >> 16) & 1);   // RNE
    return (u16)(r >> 16);
}

// ---------------- Kernel 1: mod[b][i] = t[b,:] . mod_w[i,:] + mod_b[i] ----------------
__global__ void mod_kernel(const float* __restrict__ t, const float* __restrict__ mod_w,
                           const float* __restrict__ mod_b, float* __restrict__ mod) {
    int g = blockIdx.x, b = blockIdx.y;
    int lane = threadIdx.x & 63, wv = threadIdx.x >> 6;
    const float* tb = t + b * T_;
    #pragma unroll
    for (int q = 0; q < 4; ++q) {
        int i = g * 16 + wv * 4 + q;
        const float* wr = mod_w + (size_t)i * T_;
        float s = 0.f;
        #pragma unroll
        for (int u = 0; u < 8; ++u) s += wr[lane + u * 64] * tb[lane + u * 64];
        #pragma unroll
        for (int d = 32; d; d >>= 1) s += __shfl_down(s, d);
        if (lane == 0) mod[b * I_ + i] = s + mod_b[i];
    }
}

// ---------------- Kernel 2: Wb[b][o][i] = bf16( proj_w[o,i]*(mod[b,i]+1) * demod[b,o] ) ----
__global__ void wmod_kernel(const float* __restrict__ proj_w, const float* __restrict__ mod,
                            u16* __restrict__ Wb) {
    int og = blockIdx.x, b = blockIdx.y;
    int lane = threadIdx.x & 63, wv = threadIdx.x >> 6;
    const float* mrow = mod + b * I_;
    #pragma unroll
    for (int q = 0; q < 4; ++q) {
        int o = og * 16 + wv * 4 + q;
        const float* pw = proj_w + (size_t)o * I_;
        float4 pv = *(const float4*)(pw + lane * 4);
        float4 mv = *(const float4*)(mrow + lane * 4);
        float v0 = pv.x * (mv.x + 1.f);
        float v1 = pv.y * (mv.y + 1.f);
        float v2 = pv.z * (mv.z + 1.f);
        float v3 = pv.w * (mv.w + 1.f);
        float ss = v0*v0 + v1*v1 + v2*v2 + v3*v3;
        #pragma unroll
        for (int d = 32; d; d >>= 1) ss += __shfl_xor(ss, d);
        float dem = rsqrtf(ss + 1e-8f);
        u32 lo = (u32)f2bf(v0 * dem) | ((u32)f2bf(v1 * dem) << 16);
        u32 hi = (u32)f2bf(v2 * dem) | ((u32)f2bf(v3 * dem) << 16);
        *(uint2*)(Wb + (size_t)(b * O_ + o) * I_ + lane * 4) = make_uint2(lo, hi);
    }
}

// ---------------- Kernel 3: fused conv + GEMM, BN=32, 4 chunks of 64ch ----------------
// R13 post-mortem: DMA staging fixed per-wave load ILP, but phase-lockstep at 2 blocks/CU
// left HBM read/write pipes alternating idle (phase-serial floor ~90us). This version
// shrinks LDS to 27.1KB (Xf 10.2 + Xs 16.9) and caps VGPR at 128 -> 4 blocks/CU, 4096
// blocks of short phases: independent blocks in different phases keep fetch AND write
// streams busy simultaneously (m114 wave-level co-scheduling), no race-prone raw barriers.
__global__ __launch_bounds__(256, 4) void main_kernel(
    const float* __restrict__ bx, const float* __restrict__ conv_w,
    const u16* __restrict__ Wb, const float* __restrict__ proj_b,
    float* __restrict__ out)
{
    __shared__ __align__(16) float Xf[XFN];       // 10,240 B
    __shared__ __align__(16) u16 Xs[BN * LDK];    // 16,896 B

    const int tile = blockIdx.x;
    const int b = blockIdx.y;
    const int l0 = tile * BN;
    const int tid = threadIdx.x;
    const int lane = tid & 63;
    const int wv = tid >> 6;
    const int mlane = lane & 15;
    const int quad = lane >> 4;
    const float* bxr = bx + (size_t)b * I_ * L_;

    const int ch_init = tid / XFS;
    const int col_init = tid - ch_init * XFS;

    for (int ck = 0; ck < 4; ++ck) {
        const int ci0 = ck << 6;   // 0,64,128,192

        // ---- async stage: Xf[ch*39+col] = bx[ci0+ch][clamp(l0-4+col)] ----
        {
            int ch = ch_init, col = col_init;
            #pragma unroll
            for (int k = 0; k < 10; ++k) {
                int chc = ch < 63 ? ch : 63;                 // tail pad rows -> safe dup
                int p = l0 - 4 + col;
                p = p < 0 ? 0 : (p > L_ - 1 ? L_ - 1 : p);   // clamp; edges fixed below
                const float* gp = bxr + (size_t)(ci0 + chc) * L_ + p;
                __builtin_amdgcn_global_load_lds(
                    (const __attribute__((address_space(1))) u32*)gp,
                    (__attribute__((address_space(3))) u32*)&Xf[k * 256 + tid], 4, 0, 0);
                ch += 6; col += 22;                          // f += 256 (256 = 6*39 + 22)
                if (col >= XFS) { col -= XFS; ch += 1; }
            }
        }
        __syncthreads();   // drains vmcnt: all DMA landed

        // ---- edge zero-fix ('same' padding semantics) ----
        if (tile == 0) {
            for (int z = tid; z < 64 * 4; z += 256)
                Xf[(z >> 2) * XFS + (z & 3)] = 0.f;          // cols 0..3 <=> l = -4..-1
            __syncthreads();
        } else if (tile == NTILE - 1) {
            for (int z = tid; z < 64 * 3; z += 256) {
                int r = z / 3;
                Xf[r * XFS + 36 + (z - r * 3)] = 0.f;        // cols 36..38 <=> l >= 8192
            }
            __syncthreads();
        }

        // ---- conv from LDS: thread = (chl = tid&63, 8 outputs at s8 = (tid>>6)*8) ----
        {
            const int chl = tid & 63;
            const int s8 = (tid >> 6) << 3;                  // 0,8,16,24 (wave-uniform)
            const int ig = ci0 + chl;
            float w[K_];
            #pragma unroll
            for (int j = 0; j < K_; ++j) w[j] = conv_w[ig * K_ + j];
            const float* xr = &Xf[chl * XFS];
            float x[14];
            #pragma unroll
            for (int m = 0; m < 14; ++m) x[m] = xr[s8 + 1 + m];   // cols s8+1 .. s8+14
            #pragma unroll
            for (int n = 0; n < 8; ++n) {                    // output l = l0 + s8 + n
                float s = 0.f;
                #pragma unroll
                for (int j = 0; j < K_; ++j) s += w[j] * x[n + j];
                Xs[(s8 + n) * LDK + ig] = f2bf(s);
            }
        }
        __syncthreads();   // guards next chunk's Xf overwrite / GEMM's Xs reads
    }

    // ---- Phase 2: GEMM (BN=32: 4 m-frags x 2 n-frags per wave) ----
    f32x4 acc[4][2];
    #pragma unroll
    for (int r = 0; r < 4; ++r)
        #pragma unroll
        for (int c = 0; c < 2; ++c)
            acc[r][c] = (f32x4){0.f, 0.f, 0.f, 0.f};

    const u16* Wrow = Wb + (size_t)(b * O_ + wv * 64 + mlane) * I_;

    for (int kb = 0; kb < 8; ++kb) {
        const int koff = kb * 32 + quad * 8;
        short8 a[4], bbf[2];
        #pragma unroll
        for (int r = 0; r < 4; ++r)
            a[r] = *(const short8*)(Wrow + r * 16 * I_ + koff);
        #pragma unroll
        for (int c = 0; c < 2; ++c)
            bbf[c] = *(const short8*)(&Xs[(c * 16 + mlane) * LDK + koff]);
        #pragma unroll
        for (int r = 0; r < 4; ++r)
            #pragma unroll
            for (int c = 0; c < 2; ++c)
                acc[r][c] = __builtin_amdgcn_mfma_f32_16x16x32_bf16(a[r], bbf[c], acc[r][c], 0, 0, 0);
    }

    // ---- Epilogue: + proj_b, store ----
    float* outb = out + (size_t)b * O_ * L_;
    #pragma unroll
    for (int r = 0; r < 4; ++r) {
        const int obase = wv * 64 + r * 16 + quad * 4;
        #pragma unroll
        for (int p = 0; p < 4; ++p) {
            const int o = obase + p;
            const float bias = proj_b[o];
            float* orow = outb + (size_t)o * L_ + l0 + mlane;
            #pragma unroll
            for (int c = 0; c < 2; ++c)
                orow[c * 16] = acc[r][c][p] + bias;
        }
    }
}

extern "C" void kernel_launch(void* const* d_in, const int* in_sizes, int n_in,
                              void* d_out, int out_size, void* d_ws, size_t ws_size,
                              hipStream_t stream) {
    const float* bx     = (const float*)d_in[0];
    const float* t      = (const float*)d_in[1];
    const float* conv_w = (const float*)d_in[2];
    const float* proj_w = (const float*)d_in[3];
    const float* proj_b = (const float*)d_in[4];
    const float* mod_w  = (const float*)d_in[5];
    const float* mod_b  = (const float*)d_in[6];
    float* out = (float*)d_out;

    float* mod = (float*)d_ws;                       // 16 KB
    u16*   Wb  = (u16*)((char*)d_ws + 16384);        // 2 MB bf16 modulated weights

    mod_kernel<<<dim3(16, 16), 256, 0, stream>>>(t, mod_w, mod_b, mod);
    wmod_kernel<<<dim3(16, 16), 256, 0, stream>>>(proj_w, mod, Wb);
    main_kernel<<<dim3(NTILE, 16), 256, 0, stream>>>(bx, conv_w, Wb, proj_b, out);
}